// Round 12
// baseline (729.086 us; speedup 1.0000x reference)
//
#include <hip/hip_runtime.h>
#include <stdint.h>

#define N_TOK 8192
#define C_DIM 1024
#define H_DIM 3072
#define N_EXP 8
#define N_ASSIGN (N_TOK * 2)

typedef __attribute__((ext_vector_type(8))) short short8;
typedef __attribute__((ext_vector_type(4))) float f32x4;

__device__ __forceinline__ unsigned short f2bf(float f) {
    union { float f; uint32_t u; } v; v.f = f;
    uint32_t r = (v.u + 0x7FFFu + ((v.u >> 16) & 1u)) >> 16;
    return (unsigned short)r;
}

#define GLDS16(SRC, DST) __builtin_amdgcn_global_load_lds( \
    (const __attribute__((address_space(1))) void*)(SRC),  \
    (__attribute__((address_space(3))) void*)(DST), 16, 0, 0)

// ---------------- fused transpose + fp32->bf16 for BOTH weight tensors.
__global__ __launch_bounds__(256) void transpose_both_kernel(const float* __restrict__ W1,
                                                             const float* __restrict__ W2,
                                                             unsigned short* __restrict__ o1,
                                                             unsigned short* __restrict__ o2) {
    __shared__ float tile[64][65];
    int z = blockIdx.z;
    const float* ip;
    unsigned short* op;
    int rows, cols, c0, r0;
    if (z < 8) {
        ip = W1 + (size_t)z * C_DIM * H_DIM;
        op = o1 + (size_t)z * C_DIM * H_DIM;
        rows = C_DIM; cols = H_DIM;
        c0 = blockIdx.x * 64; r0 = blockIdx.y * 64;
    } else {
        ip = W2 + (size_t)(z - 8) * C_DIM * H_DIM;
        op = o2 + (size_t)(z - 8) * C_DIM * H_DIM;
        rows = H_DIM; cols = C_DIM;
        c0 = blockIdx.y * 64; r0 = blockIdx.x * 64;
    }
    int t = threadIdx.x;
    int lr = t >> 4, lc4 = t & 15;
#pragma unroll
    for (int it = 0; it < 4; it++) {
        int r = lr + it * 16;
        float4 v = *(const float4*)&ip[(size_t)(r0 + r) * cols + c0 + lc4 * 4];
        tile[lc4 * 4 + 0][r] = v.x;
        tile[lc4 * 4 + 1][r] = v.y;
        tile[lc4 * 4 + 2][r] = v.z;
        tile[lc4 * 4 + 3][r] = v.w;
    }
    __syncthreads();
#pragma unroll
    for (int it = 0; it < 4; it++) {
        int oc = lr + it * 16;
        ushort4 o;
        o.x = f2bf(tile[oc][lc4 * 4 + 0]);
        o.y = f2bf(tile[oc][lc4 * 4 + 1]);
        o.z = f2bf(tile[oc][lc4 * 4 + 2]);
        o.w = f2bf(tile[oc][lc4 * 4 + 3]);
        *(ushort4*)&op[(size_t)(c0 + oc) * rows + r0 + lc4 * 4] = o;
    }
}

// ---------------- router
__global__ __launch_bounds__(256) void router_kernel(const float* __restrict__ x, const float* __restrict__ Wr,
                                                     int2* __restrict__ idx2, float2* __restrict__ wgt2,
                                                     float* __restrict__ piAcc, int* __restrict__ cntAcc) {
    __shared__ float s_pi[8];
    __shared__ int s_cnt[8];
    int t = threadIdx.x;
    if (t < 8) { s_pi[t] = 0.f; s_cnt[t] = 0; }
    __syncthreads();
    int lane = t & 63;
    int wid = t >> 6;
    int gwv = blockIdx.x * 4 + wid;
    int nw = gridDim.x * 4;
    for (int n = gwv; n < N_TOK; n += nw) {
        float acc[8];
#pragma unroll
        for (int e = 0; e < 8; e++) acc[e] = 0.f;
        const float* xr = x + (size_t)n * C_DIM;
#pragma unroll
        for (int j = 0; j < 16; j++) {
            int k = lane + 64 * j;
            float xv = xr[k];
            const float4* wr4 = (const float4*)(Wr + (size_t)k * 8);
            float4 a = wr4[0], b = wr4[1];
            acc[0] += xv * a.x; acc[1] += xv * a.y; acc[2] += xv * a.z; acc[3] += xv * a.w;
            acc[4] += xv * b.x; acc[5] += xv * b.y; acc[6] += xv * b.z; acc[7] += xv * b.w;
        }
#pragma unroll
        for (int off = 1; off < 64; off <<= 1) {
#pragma unroll
            for (int e = 0; e < 8; e++) acc[e] += __shfl_xor(acc[e], off, 64);
        }
        float m = acc[0];
#pragma unroll
        for (int e = 1; e < 8; e++) m = fmaxf(m, acc[e]);
        float p[8]; float s = 0.f;
#pragma unroll
        for (int e = 0; e < 8; e++) { p[e] = __expf(acc[e] - m); s += p[e]; }
        float inv = 1.f / s;
#pragma unroll
        for (int e = 0; e < 8; e++) p[e] *= inv;
        int i0 = 0; float l0 = acc[0];
#pragma unroll
        for (int e = 1; e < 8; e++) if (acc[e] > l0) { l0 = acc[e]; i0 = e; }
        int i1 = -1; float l1 = -1e30f;
#pragma unroll
        for (int e = 0; e < 8; e++) if (e != i0 && acc[e] > l1) { l1 = acc[e]; i1 = e; }
        if (lane == 0) {
            float v0 = p[i0], v1 = p[i1];
            float rs = 1.f / (v0 + v1);
            idx2[n] = make_int2(i0, i1);
            wgt2[n] = make_float2(v0 * rs, v1 * rs);
            atomicAdd(&s_cnt[i0], 1);
            atomicAdd(&s_cnt[i1], 1);
#pragma unroll
            for (int e = 0; e < 8; e++) atomicAdd(&s_pi[e], p[e]);
        }
    }
    __syncthreads();
    if (t < 8) { atomicAdd(&piAcc[t], s_pi[t]); atomicAdd(&cntAcc[t], s_cnt[t]); }
}

// ---------------- offsets + aux loss
__global__ void finalize_router_kernel(const int* __restrict__ cnt, const float* __restrict__ pi,
                                       int* __restrict__ off, float* __restrict__ aux_out) {
    if (threadIdx.x == 0) {
        int o = 0;
        float dot = 0.f;
        for (int e = 0; e < 8; e++) {
            off[e] = o;
            o += cnt[e];
            dot += (float)cnt[e] * pi[e];
        }
        aux_out[0] = 0.01f * 8.f * dot / ((float)N_TOK * (float)N_TOK);
    }
}

// ---------------- scatter
__global__ __launch_bounds__(256) void scatter_kernel(const int2* __restrict__ idx2, const float2* __restrict__ wgt2,
                                                      const int* __restrict__ off, int* __restrict__ cursor,
                                                      int* __restrict__ tok, float* __restrict__ gwArr) {
    __shared__ int lcnt[8], lbase[8];
    int t = threadIdx.x;
    if (t < 8) lcnt[t] = 0;
    __syncthreads();
    int a = blockIdx.x * 256 + t;
    int n = a >> 1, k = a & 1;
    int2 id = idx2[n];
    float2 w = wgt2[n];
    int e = k ? id.y : id.x;
    float wv = k ? w.y : w.x;
    int rank = atomicAdd(&lcnt[e], 1);
    __syncthreads();
    if (t < 8) lbase[t] = atomicAdd(&cursor[t], lcnt[t]);
    __syncthreads();
    int pos = off[e] + lbase[e] + rank;
    tok[pos] = n;
    gwArr[pos] = wv;
}

// ---------------- gather
__global__ __launch_bounds__(256) void gather_kernel(const float* __restrict__ x, const int* __restrict__ tok,
                                                     unsigned short* __restrict__ xg) {
    int wid = threadIdx.x >> 6, lane = threadIdx.x & 63;
    int row = blockIdx.x * 4 + wid;
    int n = tok[row];
    const float4* src = (const float4*)(x + (size_t)n * C_DIM);
    ushort4* dst = (ushort4*)(xg + (size_t)row * C_DIM);
#pragma unroll
    for (int j = 0; j < 4; j++) {
        float4 v = src[lane + 64 * j];
        ushort4 o;
        o.x = f2bf(v.x); o.y = f2bf(v.y); o.z = f2bf(v.z); o.w = f2bf(v.w);
        dst[lane + 64 * j] = o;
    }
}

// ---------------- grouped GEMM: R7 frame (BK=64, single-buffer LDS, plain
// stage -> syncthreads -> compute -> syncthreads), GEOMETRY change only:
// BM=128 x BN=256, 4 waves with 64x128 wave-tiles (acc[4][8] -> 128 AGPR).
// LDS traffic per block-step: read 96 KB + write 48 KB for 4.2 MFLOP
// = 34 B/kFLOP vs R7's 45.7 — the experiment: is LDS bandwidth the pacer?
// LDS 48 KB/block -> 2 blocks/CU (combined reg ~244 -> 2 waves/SIMD).
// Swizzle (R7-proven): rows = 64 shorts = 128 B; within-row chunk permute
// sc = pos ^ (row&7) on SOURCE and READ; contiguous 1-KiB wave staging,
// 0 bank conflicts. Work: flat (e, mblk, y, s) + bijective XCD remap.
// EPI=0: hs = bf16(silu(acc)); EPI=1: atomicAdd(out[tok*C+c], gw*acc)
template <int EPI>
__global__ __launch_bounds__(256) void moe_gemm_kernel(
    const unsigned short* __restrict__ A, int ldA,
    const unsigned short* __restrict__ Bt, int ldB, int bRowOff, int bColOff,
    int Kseg, int NY, int SK,
    const int* __restrict__ cnt, const int* __restrict__ off,
    const int* __restrict__ tok, const float* __restrict__ gwArr,
    unsigned short* __restrict__ hs, int ldH,
    float* __restrict__ out) {
    __shared__ unsigned short As[8192];    // [128][64] shorts = 16 KiB
    __shared__ unsigned short Bs[16384];   // [256][64] shorts = 32 KiB

    // ---- flat work total + bijective XCD remap
    int nbs[8];
    int tot = 0;
#pragma unroll
    for (int i = 0; i < 8; i++) {
        nbs[i] = (cnt[i] + 127) >> 7;
        tot += nbs[i] * NY * SK;
    }
    int p = blockIdx.x;
    int q = tot >> 3, r = tot & 7;
    int xx = p & 7, sp = p >> 3;
    int capx = (xx < r) ? q + 1 : q;
    if (sp >= capx) return;
    int wi = (xx < r) ? xx * (q + 1) + sp : r * (q + 1) + (xx - r) * q + sp;

    // ---- decode wi -> (e, mblk, y, s); mb-inner for B-stripe L2 reuse
    int base = 0, e = -1, enb = 0, local = 0;
#pragma unroll
    for (int i = 0; i < 8; i++) {
        int sz = nbs[i] * NY * SK;
        if (e < 0 && wi < base + sz) { e = i; enb = nbs[i]; local = wi - base; }
        base += sz;
    }
    if (e < 0) return;
    int ys = local / enb;
    int mblk = local - ys * enb;
    int s = ys / NY;
    int y = ys - s * NY;
    int M = cnt[e];
    int m0 = mblk * 128;
    int baseRow = off[e];
    int n0 = y * 256;
    int acol = s * Kseg;
    int bcol = bColOff + s * Kseg;

    int tid = threadIdx.x;
    int lane = tid & 63;
    int wid = tid >> 6;
    int wm = (wid >> 1) * 64;    // 2 wave-rows of 64
    int wn = (wid & 1) * 128;    // 2 wave-cols of 128

    f32x4 acc[4][8];
#pragma unroll
    for (int i = 0; i < 4; i++)
#pragma unroll
        for (int j = 0; j < 8; j++) acc[i][j] = (f32x4)0.f;

    const unsigned short* Bex = Bt + (size_t)e * (size_t)(C_DIM * H_DIM);

    // ---- staging. A tile: 128 rows x 8 chunks = 1024 -> 4/thread.
    // B tile: 256 rows x 8 chunks = 2048 -> 8/thread.
    // chunk c: row=c>>3, pos=c&7, src chunk = pos ^ (row&7).
    const unsigned short* srcA[4];
    const unsigned short* srcB[8];
    int ldsA[4], ldsB[8];
#pragma unroll
    for (int i = 0; i < 4; i++) {
        int c = i * 256 + tid;
        int row = c >> 3;
        int sc = (c & 7) ^ (row & 7);
        int rg = m0 + row; if (rg > M - 1) rg = M - 1;
        srcA[i] = A + (size_t)(baseRow + rg) * ldA + acol + sc * 8;
        ldsA[i] = (c & ~63) * 8;
    }
#pragma unroll
    for (int i = 0; i < 8; i++) {
        int c = i * 256 + tid;
        int row = c >> 3;
        int sc = (c & 7) ^ (row & 7);
        srcB[i] = Bex + (size_t)(bRowOff + n0 + row) * ldB + bcol + sc * 8;
        ldsB[i] = (c & ~63) * 8;
    }

    // ---- swizzled read offsets (shorts): row rr, k-chunk (kk*4+kq) -> ^(rr&7)
    int kq = lane >> 4;
    int rsub = lane & 15;
    int offAr[2][4], offBr[2][8];
#pragma unroll
    for (int kk = 0; kk < 2; kk++) {
#pragma unroll
        for (int m = 0; m < 4; m++) {
            int rr = wm + m * 16 + rsub;
            offAr[kk][m] = rr * 64 + (((kk * 4 + kq) ^ (rr & 7)) * 8);
        }
#pragma unroll
        for (int n = 0; n < 8; n++) {
            int rn = wn + n * 16 + rsub;
            offBr[kk][n] = rn * 64 + (((kk * 4 + kq) ^ (rn & 7)) * 8);
        }
    }

    int nt = Kseg >> 6;
#pragma unroll 1
    for (int t = 0; t < nt; ++t) {
#pragma unroll
        for (int i = 0; i < 4; i++) { GLDS16(srcA[i], &As[ldsA[i]]); srcA[i] += 64; }
#pragma unroll
        for (int i = 0; i < 8; i++) { GLDS16(srcB[i], &Bs[ldsB[i]]); srcB[i] += 64; }
        __syncthreads();
#pragma unroll
        for (int kk = 0; kk < 2; kk++) {
            short8 a[4], b[8];
#pragma unroll
            for (int m = 0; m < 4; m++) a[m] = *(const short8*)&As[offAr[kk][m]];
#pragma unroll
            for (int n = 0; n < 8; n++) b[n] = *(const short8*)&Bs[offBr[kk][n]];
#pragma unroll
            for (int m = 0; m < 4; m++)
#pragma unroll
                for (int n = 0; n < 8; n++)
                    acc[m][n] = __builtin_amdgcn_mfma_f32_16x16x32_bf16(a[m], b[n], acc[m][n], 0, 0, 0);
        }
        __syncthreads();
    }

    // ---- epilogue
    int gRow = (lane >> 4) * 4;
    int cLane = lane & 15;
#pragma unroll
    for (int m = 0; m < 4; m++) {
#pragma unroll
        for (int j = 0; j < 4; j++) {
            int rr = m0 + wm + m * 16 + gRow + j;
            if (rr < M) {
                if (EPI == 0) {
#pragma unroll
                    for (int n = 0; n < 8; n++) {
                        int c = n0 + wn + n * 16 + cLane;
                        float v = acc[m][n][j];
                        float sv = v / (1.f + __expf(-v));
                        hs[(size_t)(baseRow + rr) * ldH + c] = f2bf(sv);
                    }
                } else {
                    int token = tok[baseRow + rr];
                    float w = gwArr[baseRow + rr];
#pragma unroll
                    for (int n = 0; n < 8; n++) {
                        int c = n0 + wn + n * 16 + cLane;
                        atomicAdd(&out[(size_t)token * C_DIM + c], w * acc[m][n][j]);
                    }
                }
            }
        }
    }
}

extern "C" void kernel_launch(void* const* d_in, const int* in_sizes, int n_in,
                              void* d_out, int out_size, void* d_ws, size_t ws_size,
                              hipStream_t stream) {
    const float* x = (const float*)d_in[0];
    const float* W1 = (const float*)d_in[1];
    const float* W2 = (const float*)d_in[2];
    const float* Wr = (const float*)d_in[3];
    float* out = (float*)d_out;

    char* p = (char*)d_ws;
    auto alloc = [&](size_t bytes) {
        char* r = p;
        p += (bytes + 255) & ~(size_t)255;
        return r;
    };
    float* pi = (float*)alloc(8 * sizeof(float));
    int* cntA = (int*)alloc(8 * sizeof(int));
    int* cursor = (int*)alloc(8 * sizeof(int));
    int* offA = (int*)alloc(8 * sizeof(int));
    int2* idx2 = (int2*)alloc((size_t)N_TOK * sizeof(int2));
    float2* wgt2 = (float2*)alloc((size_t)N_TOK * sizeof(float2));
    int* tok = (int*)alloc((size_t)N_ASSIGN * sizeof(int));
    float* gwA = (float*)alloc((size_t)N_ASSIGN * sizeof(float));
    unsigned short* W1bT = (unsigned short*)alloc((size_t)N_EXP * C_DIM * H_DIM * 2);
    unsigned short* W2bT = (unsigned short*)alloc((size_t)N_EXP * C_DIM * H_DIM * 2);
    unsigned short* xg = (unsigned short*)alloc((size_t)N_ASSIGN * C_DIM * 2);
    size_t used = (size_t)(p - (char*)d_ws);
    size_t remain = ws_size > used ? ws_size - used : 0;
    int HC = H_DIM;
    while (HC > 768 && (size_t)N_ASSIGN * HC * 2 > remain) HC >>= 1;
    unsigned short* hs = (unsigned short*)p;

    hipMemsetAsync(d_ws, 0, 1024, stream);                                      // pi, cnt, cursor, off
    hipMemsetAsync(d_out, 0, (size_t)N_TOK * C_DIM * sizeof(float), stream);    // accumulated output

    transpose_both_kernel<<<dim3(48, 16, 16), 256, 0, stream>>>(W1, W2, W1bT, W2bT);

    router_kernel<<<256, 256, 0, stream>>>(x, Wr, idx2, wgt2, pi, cntA);
    finalize_router_kernel<<<1, 64, 0, stream>>>(cntA, pi, offA, out + (size_t)N_TOK * C_DIM);
    scatter_kernel<<<N_ASSIGN / 256, 256, 0, stream>>>(idx2, wgt2, offA, cursor, tok, gwA);
    gather_kernel<<<N_ASSIGN / 4, 256, 0, stream>>>(x, tok, xg);

    // max non-empty logical blocks: sum_e ceil(M_e/128) <= 16384/128 + 7 = 135
    int nChunks = H_DIM / HC;
    for (int ci = 0; ci < nChunks; ++ci) {
        int h0 = ci * HC;
        int ny1 = HC / 256;                 // BN = 256
        int sk2 = 3;                        // Kseg = HC/3 (1024 at HC=3072), %64==0
        // GEMM1: [M_e x C] @ W1^T[H x C] -> silu -> hs[. x HC]; K=1024
        moe_gemm_kernel<0><<<dim3(135 * ny1 + 8, 1, 1), 256, 0, stream>>>(
            xg, C_DIM, W1bT, C_DIM, h0, 0, C_DIM, ny1, 1,
            cntA, offA, tok, gwA, hs, HC, out);
        // GEMM2: [M_e x HC] @ W2^T[C x H] -> scaled atomic scatter; split-K=3
        moe_gemm_kernel<1><<<dim3(135 * 4 * sk2 + 8, 1, 1), 256, 0, stream>>>(
            hs, HC, W2bT, H_DIM, 0, h0, HC / sk2, 4, sk2,
            cntA, offA, tok, gwA, hs, HC, out);
    }
}

// Round 13
// 450.298 us; speedup vs baseline: 1.6191x; 1.6191x over previous
//
#include <hip/hip_runtime.h>
#include <stdint.h>

#define N_TOK 8192
#define C_DIM 1024
#define H_DIM 3072
#define N_EXP 8
#define N_ASSIGN (N_TOK * 2)

typedef __attribute__((ext_vector_type(8))) short short8;
typedef __attribute__((ext_vector_type(4))) float f32x4;

__device__ __forceinline__ unsigned short f2bf(float f) {
    union { float f; uint32_t u; } v; v.f = f;
    uint32_t r = (v.u + 0x7FFFu + ((v.u >> 16) & 1u)) >> 16;
    return (unsigned short)r;
}

#define GLDS16(SRC, DST) __builtin_amdgcn_global_load_lds( \
    (const __attribute__((address_space(1))) void*)(SRC),  \
    (__attribute__((address_space(3))) void*)(DST), 16, 0, 0)

// ---------------- fused transpose + fp32->bf16 for BOTH weight tensors (R10-proven).
// z<8: W1 expert z (rows=C, cols=H); z>=8: W2 expert z-8 (rows=H, cols=C).
__global__ __launch_bounds__(256) void transpose_both_kernel(const float* __restrict__ W1,
                                                             const float* __restrict__ W2,
                                                             unsigned short* __restrict__ o1,
                                                             unsigned short* __restrict__ o2) {
    __shared__ float tile[64][65];
    int z = blockIdx.z;
    const float* ip;
    unsigned short* op;
    int rows, cols, c0, r0;
    if (z < 8) {
        ip = W1 + (size_t)z * C_DIM * H_DIM;
        op = o1 + (size_t)z * C_DIM * H_DIM;
        rows = C_DIM; cols = H_DIM;
        c0 = blockIdx.x * 64; r0 = blockIdx.y * 64;
    } else {
        ip = W2 + (size_t)(z - 8) * C_DIM * H_DIM;
        op = o2 + (size_t)(z - 8) * C_DIM * H_DIM;
        rows = H_DIM; cols = C_DIM;
        c0 = blockIdx.y * 64; r0 = blockIdx.x * 64;
    }
    int t = threadIdx.x;
    int lr = t >> 4, lc4 = t & 15;
#pragma unroll
    for (int it = 0; it < 4; it++) {
        int r = lr + it * 16;
        float4 v = *(const float4*)&ip[(size_t)(r0 + r) * cols + c0 + lc4 * 4];
        tile[lc4 * 4 + 0][r] = v.x;
        tile[lc4 * 4 + 1][r] = v.y;
        tile[lc4 * 4 + 2][r] = v.z;
        tile[lc4 * 4 + 3][r] = v.w;
    }
    __syncthreads();
#pragma unroll
    for (int it = 0; it < 4; it++) {
        int oc = lr + it * 16;
        ushort4 o;
        o.x = f2bf(tile[oc][lc4 * 4 + 0]);
        o.y = f2bf(tile[oc][lc4 * 4 + 1]);
        o.z = f2bf(tile[oc][lc4 * 4 + 2]);
        o.w = f2bf(tile[oc][lc4 * 4 + 3]);
        *(ushort4*)&op[(size_t)(c0 + oc) * rows + r0 + lc4 * 4] = o;
    }
}

// ---------------- router: logits = x @ Wr, softmax, top-2 (lowest-index ties), renorm; pi/cnt stats
__global__ __launch_bounds__(256) void router_kernel(const float* __restrict__ x, const float* __restrict__ Wr,
                                                     int2* __restrict__ idx2, float2* __restrict__ wgt2,
                                                     float* __restrict__ piAcc, int* __restrict__ cntAcc) {
    __shared__ float s_pi[8];
    __shared__ int s_cnt[8];
    int t = threadIdx.x;
    if (t < 8) { s_pi[t] = 0.f; s_cnt[t] = 0; }
    __syncthreads();
    int lane = t & 63;
    int wid = t >> 6;
    int gwv = blockIdx.x * 4 + wid;
    int nw = gridDim.x * 4;
    for (int n = gwv; n < N_TOK; n += nw) {
        float acc[8];
#pragma unroll
        for (int e = 0; e < 8; e++) acc[e] = 0.f;
        const float* xr = x + (size_t)n * C_DIM;
#pragma unroll
        for (int j = 0; j < 16; j++) {
            int k = lane + 64 * j;
            float xv = xr[k];
            const float4* wr4 = (const float4*)(Wr + (size_t)k * 8);
            float4 a = wr4[0], b = wr4[1];
            acc[0] += xv * a.x; acc[1] += xv * a.y; acc[2] += xv * a.z; acc[3] += xv * a.w;
            acc[4] += xv * b.x; acc[5] += xv * b.y; acc[6] += xv * b.z; acc[7] += xv * b.w;
        }
#pragma unroll
        for (int off = 1; off < 64; off <<= 1) {
#pragma unroll
            for (int e = 0; e < 8; e++) acc[e] += __shfl_xor(acc[e], off, 64);
        }
        float m = acc[0];
#pragma unroll
        for (int e = 1; e < 8; e++) m = fmaxf(m, acc[e]);
        float p[8]; float s = 0.f;
#pragma unroll
        for (int e = 0; e < 8; e++) { p[e] = __expf(acc[e] - m); s += p[e]; }
        float inv = 1.f / s;
#pragma unroll
        for (int e = 0; e < 8; e++) p[e] *= inv;
        int i0 = 0; float l0 = acc[0];
#pragma unroll
        for (int e = 1; e < 8; e++) if (acc[e] > l0) { l0 = acc[e]; i0 = e; }
        int i1 = -1; float l1 = -1e30f;
#pragma unroll
        for (int e = 0; e < 8; e++) if (e != i0 && acc[e] > l1) { l1 = acc[e]; i1 = e; }
        if (lane == 0) {
            float v0 = p[i0], v1 = p[i1];
            float rs = 1.f / (v0 + v1);
            idx2[n] = make_int2(i0, i1);
            wgt2[n] = make_float2(v0 * rs, v1 * rs);
            atomicAdd(&s_cnt[i0], 1);
            atomicAdd(&s_cnt[i1], 1);
#pragma unroll
            for (int e = 0; e < 8; e++) atomicAdd(&s_pi[e], p[e]);
        }
    }
    __syncthreads();
    if (t < 8) { atomicAdd(&piAcc[t], s_pi[t]); atomicAdd(&cntAcc[t], s_cnt[t]); }
}

// ---------------- offsets (exclusive scan of cnt) + aux loss
__global__ void finalize_router_kernel(const int* __restrict__ cnt, const float* __restrict__ pi,
                                       int* __restrict__ off, float* __restrict__ aux_out) {
    if (threadIdx.x == 0) {
        int o = 0;
        float dot = 0.f;
        for (int e = 0; e < 8; e++) {
            off[e] = o;
            o += cnt[e];
            dot += (float)cnt[e] * pi[e];
        }
        aux_out[0] = 0.01f * 8.f * dot / ((float)N_TOK * (float)N_TOK);
    }
}

// ---------------- scatter: build per-expert token/weight lists (block-aggregated cursors)
__global__ __launch_bounds__(256) void scatter_kernel(const int2* __restrict__ idx2, const float2* __restrict__ wgt2,
                                                      const int* __restrict__ off, int* __restrict__ cursor,
                                                      int* __restrict__ tok, float* __restrict__ gwArr) {
    __shared__ int lcnt[8], lbase[8];
    int t = threadIdx.x;
    if (t < 8) lcnt[t] = 0;
    __syncthreads();
    int a = blockIdx.x * 256 + t;
    int n = a >> 1, k = a & 1;
    int2 id = idx2[n];
    float2 w = wgt2[n];
    int e = k ? id.y : id.x;
    float wv = k ? w.y : w.x;
    int rank = atomicAdd(&lcnt[e], 1);
    __syncthreads();
    if (t < 8) lbase[t] = atomicAdd(&cursor[t], lcnt[t]);
    __syncthreads();
    int pos = off[e] + lbase[e] + rank;
    tok[pos] = n;
    gwArr[pos] = wv;
}

// ---------------- gather x rows -> packed bf16 xg (one wave per assignment row)
__global__ __launch_bounds__(256) void gather_kernel(const float* __restrict__ x, const int* __restrict__ tok,
                                                     unsigned short* __restrict__ xg) {
    int wid = threadIdx.x >> 6, lane = threadIdx.x & 63;
    int row = blockIdx.x * 4 + wid;
    int n = tok[row];
    const float4* src = (const float4*)(x + (size_t)n * C_DIM);
    ushort4* dst = (ushort4*)(xg + (size_t)row * C_DIM);
#pragma unroll
    for (int j = 0; j < 4; j++) {
        float4 v = src[lane + 64 * j];
        ushort4 o;
        o.x = f2bf(v.x); o.y = f2bf(v.y); o.z = f2bf(v.z); o.w = f2bf(v.w);
        dst[lane + 64 * j] = o;
    }
}

// ---------------- grouped GEMM, EXACT R7 (best measured: 205 us/GEMM, 450.9 total):
// m97 frame — 128x128 tile, BK=64 (row = 128 B), 4 waves (2x2), single-buffered
// 32 KiB LDS, plain stage -> syncthreads -> compute -> syncthreads.
// LDS [128][64 shorts] linear; within-row 16B-chunk permute sc = pos ^ (row&7)
// on SOURCE and READ: staging = contiguous 1-KiB wave instructions (full-line
// fetches), ds_read = 2-way bank aliasing = free (0 conflicts, PMC-verified).
// Work: flat (e, mblk, y, s[split-K]) list + bijective XCD remap (m204),
// mb-inner for B-stripe L2 reuse.
// EPI=0: hs = bf16(silu(acc)); EPI=1: atomicAdd(out[tok*C+c], gw*acc) [split-K safe]
template <int EPI>
__global__ __launch_bounds__(256) void moe_gemm_kernel(
    const unsigned short* __restrict__ A, int ldA,
    const unsigned short* __restrict__ Bt, int ldB, int bRowOff, int bColOff,
    int Kseg, int NY, int SK,
    const int* __restrict__ cnt, const int* __restrict__ off,
    const int* __restrict__ tok, const float* __restrict__ gwArr,
    unsigned short* __restrict__ hs, int ldH,
    float* __restrict__ out) {
    __shared__ unsigned short As[8192];   // [128][64] shorts = 16 KiB
    __shared__ unsigned short Bs[8192];

    // ---- flat work total + bijective XCD remap
    int nbs[8];
    int tot = 0;
#pragma unroll
    for (int i = 0; i < 8; i++) {
        nbs[i] = (cnt[i] + 127) >> 7;
        tot += nbs[i] * NY * SK;
    }
    int p = blockIdx.x;
    int q = tot >> 3, r = tot & 7;
    int xx = p & 7, sp = p >> 3;
    int capx = (xx < r) ? q + 1 : q;
    if (sp >= capx) return;
    int wi = (xx < r) ? xx * (q + 1) + sp : r * (q + 1) + (xx - r) * q + sp;

    // ---- decode wi -> (e, mblk, y, s); mb-inner for B-stripe L2 reuse
    int base = 0, e = -1, enb = 0, local = 0;
#pragma unroll
    for (int i = 0; i < 8; i++) {
        int sz = nbs[i] * NY * SK;
        if (e < 0 && wi < base + sz) { e = i; enb = nbs[i]; local = wi - base; }
        base += sz;
    }
    if (e < 0) return;
    int ys = local / enb;
    int mblk = local - ys * enb;
    int s = ys / NY;
    int y = ys - s * NY;
    int M = cnt[e];
    int m0 = mblk * 128;
    int baseRow = off[e];
    int n0 = y * 128;
    int acol = s * Kseg;
    int bcol = bColOff + s * Kseg;

    int tid = threadIdx.x;
    int lane = tid & 63;
    int wid = tid >> 6;
    int wm = (wid >> 1) * 64;
    int wn = (wid & 1) * 64;

    f32x4 acc[4][4];
#pragma unroll
    for (int i = 0; i < 4; i++)
#pragma unroll
        for (int j = 0; j < 4; j++) acc[i][j] = (f32x4)0.f;

    const unsigned short* Bex = Bt + (size_t)e * (size_t)(C_DIM * H_DIM);

    // ---- staging descriptors: 1024 chunks (16B) per matrix tile, 4 per thread.
    // chunk c: row = c>>3 (0..127), pos = c&7; source chunk = pos ^ (row&7)
    const unsigned short* srcA[4];
    const unsigned short* srcB[4];
    int ldsOff[4];
#pragma unroll
    for (int i = 0; i < 4; i++) {
        int c = i * 256 + tid;
        int row = c >> 3;
        int pos = c & 7;
        int sc = pos ^ (row & 7);
        int rg = m0 + row; if (rg > M - 1) rg = M - 1;
        srcA[i] = A + (size_t)(baseRow + rg) * ldA + acol + sc * 8;
        srcB[i] = Bex + (size_t)(bRowOff + n0 + row) * ldB + bcol + sc * 8;
        ldsOff[i] = (c & ~63) * 8;   // shorts; wave-uniform base + lane*16B implicit
    }

    // ---- swizzled read offsets (shorts): row r, k-chunk (kk*4+kq) -> ^(r&7)
    int kq = lane >> 4;
    int rsub = lane & 15;
    int offAr[2][4], offBr[2][4];
#pragma unroll
    for (int kk = 0; kk < 2; kk++) {
#pragma unroll
        for (int m = 0; m < 4; m++) {
            int rr = wm + m * 16 + rsub;
            offAr[kk][m] = rr * 64 + (((kk * 4 + kq) ^ (rr & 7)) * 8);
        }
#pragma unroll
        for (int n = 0; n < 4; n++) {
            int rn = wn + n * 16 + rsub;
            offBr[kk][n] = rn * 64 + (((kk * 4 + kq) ^ (rn & 7)) * 8);
        }
    }

    int nt = Kseg >> 6;
#pragma unroll 1
    for (int t = 0; t < nt; ++t) {
#pragma unroll
        for (int i = 0; i < 4; i++) {
            GLDS16(srcA[i], &As[ldsOff[i]]);
            GLDS16(srcB[i], &Bs[ldsOff[i]]);
            srcA[i] += 64; srcB[i] += 64;
        }
        __syncthreads();
#pragma unroll
        for (int kk = 0; kk < 2; kk++) {
            short8 a[4], b[4];
#pragma unroll
            for (int m = 0; m < 4; m++) a[m] = *(const short8*)&As[offAr[kk][m]];
#pragma unroll
            for (int n = 0; n < 4; n++) b[n] = *(const short8*)&Bs[offBr[kk][n]];
#pragma unroll
            for (int m = 0; m < 4; m++)
#pragma unroll
                for (int n = 0; n < 4; n++)
                    acc[m][n] = __builtin_amdgcn_mfma_f32_16x16x32_bf16(a[m], b[n], acc[m][n], 0, 0, 0);
        }
        __syncthreads();
    }

    int gRow = (lane >> 4) * 4;
    int cLane = lane & 15;
#pragma unroll
    for (int m = 0; m < 4; m++) {
#pragma unroll
        for (int j = 0; j < 4; j++) {
            int rr = m0 + wm + m * 16 + gRow + j;
            if (rr < M) {
                if (EPI == 0) {
#pragma unroll
                    for (int n = 0; n < 4; n++) {
                        int c = n0 + wn + n * 16 + cLane;
                        float v = acc[m][n][j];
                        float sv = v / (1.f + __expf(-v));
                        hs[(size_t)(baseRow + rr) * ldH + c] = f2bf(sv);
                    }
                } else {
                    int token = tok[baseRow + rr];
                    float w = gwArr[baseRow + rr];
#pragma unroll
                    for (int n = 0; n < 4; n++) {
                        int c = n0 + wn + n * 16 + cLane;
                        atomicAdd(&out[(size_t)token * C_DIM + c], w * acc[m][n][j]);
                    }
                }
            }
        }
    }
}

extern "C" void kernel_launch(void* const* d_in, const int* in_sizes, int n_in,
                              void* d_out, int out_size, void* d_ws, size_t ws_size,
                              hipStream_t stream) {
    const float* x = (const float*)d_in[0];
    const float* W1 = (const float*)d_in[1];
    const float* W2 = (const float*)d_in[2];
    const float* Wr = (const float*)d_in[3];
    float* out = (float*)d_out;

    char* p = (char*)d_ws;
    auto alloc = [&](size_t bytes) {
        char* r = p;
        p += (bytes + 255) & ~(size_t)255;
        return r;
    };
    float* pi = (float*)alloc(8 * sizeof(float));
    int* cntA = (int*)alloc(8 * sizeof(int));
    int* cursor = (int*)alloc(8 * sizeof(int));
    int* offA = (int*)alloc(8 * sizeof(int));
    int2* idx2 = (int2*)alloc((size_t)N_TOK * sizeof(int2));
    float2* wgt2 = (float2*)alloc((size_t)N_TOK * sizeof(float2));
    int* tok = (int*)alloc((size_t)N_ASSIGN * sizeof(int));
    float* gwA = (float*)alloc((size_t)N_ASSIGN * sizeof(float));
    unsigned short* W1bT = (unsigned short*)alloc((size_t)N_EXP * C_DIM * H_DIM * 2);
    unsigned short* W2bT = (unsigned short*)alloc((size_t)N_EXP * C_DIM * H_DIM * 2);
    unsigned short* xg = (unsigned short*)alloc((size_t)N_ASSIGN * C_DIM * 2);
    size_t used = (size_t)(p - (char*)d_ws);
    size_t remain = ws_size > used ? ws_size - used : 0;
    int HC = H_DIM;
    while (HC > 384 && (size_t)N_ASSIGN * HC * 2 > remain) HC >>= 1;
    unsigned short* hs = (unsigned short*)p;

    hipMemsetAsync(d_ws, 0, 1024, stream);                                      // pi, cnt, cursor, off
    hipMemsetAsync(d_out, 0, (size_t)N_TOK * C_DIM * sizeof(float), stream);    // accumulated output

    transpose_both_kernel<<<dim3(48, 16, 16), 256, 0, stream>>>(W1, W2, W1bT, W2bT);

    router_kernel<<<256, 256, 0, stream>>>(x, Wr, idx2, wgt2, pi, cntA);
    finalize_router_kernel<<<1, 64, 0, stream>>>(cntA, pi, offA, out + (size_t)N_TOK * C_DIM);
    scatter_kernel<<<N_ASSIGN / 256, 256, 0, stream>>>(idx2, wgt2, offA, cursor, tok, gwA);
    gather_kernel<<<N_ASSIGN / 4, 256, 0, stream>>>(x, tok, xg);

    // max non-empty logical blocks: sum_e ceil(M_e/128) <= 16384/128 + 7 = 135
    int nChunks = H_DIM / HC;
    for (int ci = 0; ci < nChunks; ++ci) {
        int h0 = ci * HC;
        int ny1 = HC / 128;
        int sk2 = (HC >= 1536) ? 2 : 1;   // Kseg = HC/sk2, multiple of 32
        // GEMM1: [M_e x C] @ W1^T[H x C] -> silu -> hs[. x HC]; K=1024
        moe_gemm_kernel<0><<<dim3(135 * ny1 + 8, 1, 1), 256, 0, stream>>>(
            xg, C_DIM, W1bT, C_DIM, h0, 0, C_DIM, ny1, 1,
            cntA, offA, tok, gwA, hs, HC, out);
        // GEMM2: [M_e x HC] @ W2^T[C x H] -> scaled atomic scatter; split-K
        moe_gemm_kernel<1><<<dim3(135 * 8 * sk2 + 8, 1, 1), 256, 0, stream>>>(
            hs, HC, W2bT, H_DIM, 0, h0, HC / sk2, 8, sk2,
            cntA, offA, tok, gwA, hs, HC, out);
    }
}

// Round 14
// 424.824 us; speedup vs baseline: 1.7162x; 1.0600x over previous
//
#include <hip/hip_runtime.h>
#include <stdint.h>

#define N_TOK 8192
#define C_DIM 1024
#define H_DIM 3072
#define N_EXP 8
#define N_ASSIGN (N_TOK * 2)

typedef __attribute__((ext_vector_type(8))) short short8;
typedef __attribute__((ext_vector_type(4))) float f32x4;

__device__ __forceinline__ unsigned short f2bf(float f) {
    union { float f; uint32_t u; } v; v.f = f;
    uint32_t r = (v.u + 0x7FFFu + ((v.u >> 16) & 1u)) >> 16;
    return (unsigned short)r;
}

#define GLDS16(SRC, DST) __builtin_amdgcn_global_load_lds( \
    (const __attribute__((address_space(1))) void*)(SRC),  \
    (__attribute__((address_space(3))) void*)(DST), 16, 0, 0)

// ---------------- fused transpose + fp32->bf16 for BOTH weight tensors (R10-proven).
__global__ __launch_bounds__(256) void transpose_both_kernel(const float* __restrict__ W1,
                                                             const float* __restrict__ W2,
                                                             unsigned short* __restrict__ o1,
                                                             unsigned short* __restrict__ o2) {
    __shared__ float tile[64][65];
    int z = blockIdx.z;
    const float* ip;
    unsigned short* op;
    int rows, cols, c0, r0;
    if (z < 8) {
        ip = W1 + (size_t)z * C_DIM * H_DIM;
        op = o1 + (size_t)z * C_DIM * H_DIM;
        rows = C_DIM; cols = H_DIM;
        c0 = blockIdx.x * 64; r0 = blockIdx.y * 64;
    } else {
        ip = W2 + (size_t)(z - 8) * C_DIM * H_DIM;
        op = o2 + (size_t)(z - 8) * C_DIM * H_DIM;
        rows = H_DIM; cols = C_DIM;
        c0 = blockIdx.y * 64; r0 = blockIdx.x * 64;
    }
    int t = threadIdx.x;
    int lr = t >> 4, lc4 = t & 15;
#pragma unroll
    for (int it = 0; it < 4; it++) {
        int r = lr + it * 16;
        float4 v = *(const float4*)&ip[(size_t)(r0 + r) * cols + c0 + lc4 * 4];
        tile[lc4 * 4 + 0][r] = v.x;
        tile[lc4 * 4 + 1][r] = v.y;
        tile[lc4 * 4 + 2][r] = v.z;
        tile[lc4 * 4 + 3][r] = v.w;
    }
    __syncthreads();
#pragma unroll
    for (int it = 0; it < 4; it++) {
        int oc = lr + it * 16;
        ushort4 o;
        o.x = f2bf(tile[oc][lc4 * 4 + 0]);
        o.y = f2bf(tile[oc][lc4 * 4 + 1]);
        o.z = f2bf(tile[oc][lc4 * 4 + 2]);
        o.w = f2bf(tile[oc][lc4 * 4 + 3]);
        *(ushort4*)&op[(size_t)(c0 + oc) * rows + r0 + lc4 * 4] = o;
    }
}

// ---------------- router: logits = x @ Wr, softmax, top-2 (lowest-index ties), renorm; pi/cnt stats
__global__ __launch_bounds__(256) void router_kernel(const float* __restrict__ x, const float* __restrict__ Wr,
                                                     int2* __restrict__ idx2, float2* __restrict__ wgt2,
                                                     float* __restrict__ piAcc, int* __restrict__ cntAcc) {
    __shared__ float s_pi[8];
    __shared__ int s_cnt[8];
    int t = threadIdx.x;
    if (t < 8) { s_pi[t] = 0.f; s_cnt[t] = 0; }
    __syncthreads();
    int lane = t & 63;
    int wid = t >> 6;
    int gwv = blockIdx.x * 4 + wid;
    int nw = gridDim.x * 4;
    for (int n = gwv; n < N_TOK; n += nw) {
        float acc[8];
#pragma unroll
        for (int e = 0; e < 8; e++) acc[e] = 0.f;
        const float* xr = x + (size_t)n * C_DIM;
#pragma unroll
        for (int j = 0; j < 16; j++) {
            int k = lane + 64 * j;
            float xv = xr[k];
            const float4* wr4 = (const float4*)(Wr + (size_t)k * 8);
            float4 a = wr4[0], b = wr4[1];
            acc[0] += xv * a.x; acc[1] += xv * a.y; acc[2] += xv * a.z; acc[3] += xv * a.w;
            acc[4] += xv * b.x; acc[5] += xv * b.y; acc[6] += xv * b.z; acc[7] += xv * b.w;
        }
#pragma unroll
        for (int off = 1; off < 64; off <<= 1) {
#pragma unroll
            for (int e = 0; e < 8; e++) acc[e] += __shfl_xor(acc[e], off, 64);
        }
        float m = acc[0];
#pragma unroll
        for (int e = 1; e < 8; e++) m = fmaxf(m, acc[e]);
        float p[8]; float s = 0.f;
#pragma unroll
        for (int e = 0; e < 8; e++) { p[e] = __expf(acc[e] - m); s += p[e]; }
        float inv = 1.f / s;
#pragma unroll
        for (int e = 0; e < 8; e++) p[e] *= inv;
        int i0 = 0; float l0 = acc[0];
#pragma unroll
        for (int e = 1; e < 8; e++) if (acc[e] > l0) { l0 = acc[e]; i0 = e; }
        int i1 = -1; float l1 = -1e30f;
#pragma unroll
        for (int e = 0; e < 8; e++) if (e != i0 && acc[e] > l1) { l1 = acc[e]; i1 = e; }
        if (lane == 0) {
            float v0 = p[i0], v1 = p[i1];
            float rs = 1.f / (v0 + v1);
            idx2[n] = make_int2(i0, i1);
            wgt2[n] = make_float2(v0 * rs, v1 * rs);
            atomicAdd(&s_cnt[i0], 1);
            atomicAdd(&s_cnt[i1], 1);
#pragma unroll
            for (int e = 0; e < 8; e++) atomicAdd(&s_pi[e], p[e]);
        }
    }
    __syncthreads();
    if (t < 8) { atomicAdd(&piAcc[t], s_pi[t]); atomicAdd(&cntAcc[t], s_cnt[t]); }
}

// ---------------- offsets (exclusive scan of cnt) + aux loss
__global__ void finalize_router_kernel(const int* __restrict__ cnt, const float* __restrict__ pi,
                                       int* __restrict__ off, float* __restrict__ aux_out) {
    if (threadIdx.x == 0) {
        int o = 0;
        float dot = 0.f;
        for (int e = 0; e < 8; e++) {
            off[e] = o;
            o += cnt[e];
            dot += (float)cnt[e] * pi[e];
        }
        aux_out[0] = 0.01f * 8.f * dot / ((float)N_TOK * (float)N_TOK);
    }
}

// ---------------- scatter: build per-expert token/weight lists (block-aggregated cursors)
__global__ __launch_bounds__(256) void scatter_kernel(const int2* __restrict__ idx2, const float2* __restrict__ wgt2,
                                                      const int* __restrict__ off, int* __restrict__ cursor,
                                                      int* __restrict__ tok, float* __restrict__ gwArr) {
    __shared__ int lcnt[8], lbase[8];
    int t = threadIdx.x;
    if (t < 8) lcnt[t] = 0;
    __syncthreads();
    int a = blockIdx.x * 256 + t;
    int n = a >> 1, k = a & 1;
    int2 id = idx2[n];
    float2 w = wgt2[n];
    int e = k ? id.y : id.x;
    float wv = k ? w.y : w.x;
    int rank = atomicAdd(&lcnt[e], 1);
    __syncthreads();
    if (t < 8) lbase[t] = atomicAdd(&cursor[t], lcnt[t]);
    __syncthreads();
    int pos = off[e] + lbase[e] + rank;
    tok[pos] = n;
    gwArr[pos] = wv;
}

// ---------------- gather x rows -> packed bf16 xg (one wave per assignment row)
__global__ __launch_bounds__(256) void gather_kernel(const float* __restrict__ x, const int* __restrict__ tok,
                                                     unsigned short* __restrict__ xg) {
    int wid = threadIdx.x >> 6, lane = threadIdx.x & 63;
    int row = blockIdx.x * 4 + wid;
    int n = tok[row];
    const float4* src = (const float4*)(x + (size_t)n * C_DIM);
    ushort4* dst = (ushort4*)(xg + (size_t)row * C_DIM);
#pragma unroll
    for (int j = 0; j < 4; j++) {
        float4 v = src[lane + 64 * j];
        ushort4 o;
        o.x = f2bf(v.x); o.y = f2bf(v.y); o.z = f2bf(v.z); o.w = f2bf(v.w);
        dst[lane + 64 * j] = o;
    }
}

// ---------------- grouped GEMM: R12 frame with ONE variable changed — 8 waves
// (2M x 4N, wave-tile 64x32, acc[4][2] = 32 AGPR) instead of 4 waves of 64x64.
// Identical: 128x128 tile, BK=64, single-buffered 32 KiB LDS, plain stage ->
// syncthreads -> compute -> syncthreads, within-row chunk permute sc = pos ^
// (row&7) on SOURCE and READ (0 conflicts), flat work list + bijective XCD
// remap, identical staging instruction stream (16 wave-instructions/tile).
// TLP experiment: doubles waves/block (9.8 -> ~20 waves/CU at same residency)
// to hide the per-step staging drain (m114 cross-wave overlap model).
// EPI=0: hs = bf16(silu(acc)); EPI=1: atomicAdd(out[tok*C+c], gw*acc) [split-K safe]
template <int EPI>
__global__ __launch_bounds__(512) void moe_gemm_kernel(
    const unsigned short* __restrict__ A, int ldA,
    const unsigned short* __restrict__ Bt, int ldB, int bRowOff, int bColOff,
    int Kseg, int NY, int SK,
    const int* __restrict__ cnt, const int* __restrict__ off,
    const int* __restrict__ tok, const float* __restrict__ gwArr,
    unsigned short* __restrict__ hs, int ldH,
    float* __restrict__ out) {
    __shared__ unsigned short As[8192];   // [128][64] shorts = 16 KiB
    __shared__ unsigned short Bs[8192];

    // ---- flat work total + bijective XCD remap
    int nbs[8];
    int tot = 0;
#pragma unroll
    for (int i = 0; i < 8; i++) {
        nbs[i] = (cnt[i] + 127) >> 7;
        tot += nbs[i] * NY * SK;
    }
    int p = blockIdx.x;
    int q = tot >> 3, r = tot & 7;
    int xx = p & 7, sp = p >> 3;
    int capx = (xx < r) ? q + 1 : q;
    if (sp >= capx) return;
    int wi = (xx < r) ? xx * (q + 1) + sp : r * (q + 1) + (xx - r) * q + sp;

    // ---- decode wi -> (e, mblk, y, s); mb-inner for B-stripe L2 reuse
    int base = 0, e = -1, enb = 0, local = 0;
#pragma unroll
    for (int i = 0; i < 8; i++) {
        int sz = nbs[i] * NY * SK;
        if (e < 0 && wi < base + sz) { e = i; enb = nbs[i]; local = wi - base; }
        base += sz;
    }
    if (e < 0) return;
    int ys = local / enb;
    int mblk = local - ys * enb;
    int s = ys / NY;
    int y = ys - s * NY;
    int M = cnt[e];
    int m0 = mblk * 128;
    int baseRow = off[e];
    int n0 = y * 128;
    int acol = s * Kseg;
    int bcol = bColOff + s * Kseg;

    int tid = threadIdx.x;
    int lane = tid & 63;
    int wid = tid >> 6;
    int wm = (wid >> 2) * 64;    // 2 wave-rows of 64
    int wn = (wid & 3) * 32;     // 4 wave-cols of 32

    f32x4 acc[4][2];
#pragma unroll
    for (int i = 0; i < 4; i++)
#pragma unroll
        for (int j = 0; j < 2; j++) acc[i][j] = (f32x4)0.f;

    const unsigned short* Bex = Bt + (size_t)e * (size_t)(C_DIM * H_DIM);

    // ---- staging descriptors: 1024 chunks (16B) per matrix tile, 2 per thread.
    // chunk c: row = c>>3 (0..127), pos = c&7; source chunk = pos ^ (row&7)
    const unsigned short* srcA[2];
    const unsigned short* srcB[2];
    int ldsOff[2];
#pragma unroll
    for (int i = 0; i < 2; i++) {
        int c = i * 512 + tid;
        int row = c >> 3;
        int pos = c & 7;
        int sc = pos ^ (row & 7);
        int rg = m0 + row; if (rg > M - 1) rg = M - 1;
        srcA[i] = A + (size_t)(baseRow + rg) * ldA + acol + sc * 8;
        srcB[i] = Bex + (size_t)(bRowOff + n0 + row) * ldB + bcol + sc * 8;
        ldsOff[i] = (c & ~63) * 8;   // shorts; wave-uniform base + lane*16B implicit
    }

    // ---- swizzled read offsets (shorts): row r, k-chunk (kk*4+kq) -> ^(r&7)
    int kq = lane >> 4;
    int rsub = lane & 15;
    int offAr[2][4], offBr[2][2];
#pragma unroll
    for (int kk = 0; kk < 2; kk++) {
#pragma unroll
        for (int m = 0; m < 4; m++) {
            int rr = wm + m * 16 + rsub;
            offAr[kk][m] = rr * 64 + (((kk * 4 + kq) ^ (rr & 7)) * 8);
        }
#pragma unroll
        for (int n = 0; n < 2; n++) {
            int rn = wn + n * 16 + rsub;
            offBr[kk][n] = rn * 64 + (((kk * 4 + kq) ^ (rn & 7)) * 8);
        }
    }

    int nt = Kseg >> 6;
#pragma unroll 1
    for (int t = 0; t < nt; ++t) {
#pragma unroll
        for (int i = 0; i < 2; i++) {
            GLDS16(srcA[i], &As[ldsOff[i]]);
            GLDS16(srcB[i], &Bs[ldsOff[i]]);
            srcA[i] += 64; srcB[i] += 64;
        }
        __syncthreads();
#pragma unroll
        for (int kk = 0; kk < 2; kk++) {
            short8 a[4], b[2];
#pragma unroll
            for (int m = 0; m < 4; m++) a[m] = *(const short8*)&As[offAr[kk][m]];
#pragma unroll
            for (int n = 0; n < 2; n++) b[n] = *(const short8*)&Bs[offBr[kk][n]];
#pragma unroll
            for (int m = 0; m < 4; m++)
#pragma unroll
                for (int n = 0; n < 2; n++)
                    acc[m][n] = __builtin_amdgcn_mfma_f32_16x16x32_bf16(a[m], b[n], acc[m][n], 0, 0, 0);
        }
        __syncthreads();
    }

    int gRow = (lane >> 4) * 4;
    int cLane = lane & 15;
#pragma unroll
    for (int m = 0; m < 4; m++) {
#pragma unroll
        for (int j = 0; j < 4; j++) {
            int rr = m0 + wm + m * 16 + gRow + j;
            if (rr < M) {
                if (EPI == 0) {
#pragma unroll
                    for (int n = 0; n < 2; n++) {
                        int c = n0 + wn + n * 16 + cLane;
                        float v = acc[m][n][j];
                        float sv = v / (1.f + __expf(-v));
                        hs[(size_t)(baseRow + rr) * ldH + c] = f2bf(sv);
                    }
                } else {
                    int token = tok[baseRow + rr];
                    float w = gwArr[baseRow + rr];
#pragma unroll
                    for (int n = 0; n < 2; n++) {
                        int c = n0 + wn + n * 16 + cLane;
                        atomicAdd(&out[(size_t)token * C_DIM + c], w * acc[m][n][j]);
                    }
                }
            }
        }
    }
}

extern "C" void kernel_launch(void* const* d_in, const int* in_sizes, int n_in,
                              void* d_out, int out_size, void* d_ws, size_t ws_size,
                              hipStream_t stream) {
    const float* x = (const float*)d_in[0];
    const float* W1 = (const float*)d_in[1];
    const float* W2 = (const float*)d_in[2];
    const float* Wr = (const float*)d_in[3];
    float* out = (float*)d_out;

    char* p = (char*)d_ws;
    auto alloc = [&](size_t bytes) {
        char* r = p;
        p += (bytes + 255) & ~(size_t)255;
        return r;
    };
    float* pi = (float*)alloc(8 * sizeof(float));
    int* cntA = (int*)alloc(8 * sizeof(int));
    int* cursor = (int*)alloc(8 * sizeof(int));
    int* offA = (int*)alloc(8 * sizeof(int));
    int2* idx2 = (int2*)alloc((size_t)N_TOK * sizeof(int2));
    float2* wgt2 = (float2*)alloc((size_t)N_TOK * sizeof(float2));
    int* tok = (int*)alloc((size_t)N_ASSIGN * sizeof(int));
    float* gwA = (float*)alloc((size_t)N_ASSIGN * sizeof(float));
    unsigned short* W1bT = (unsigned short*)alloc((size_t)N_EXP * C_DIM * H_DIM * 2);
    unsigned short* W2bT = (unsigned short*)alloc((size_t)N_EXP * C_DIM * H_DIM * 2);
    unsigned short* xg = (unsigned short*)alloc((size_t)N_ASSIGN * C_DIM * 2);
    size_t used = (size_t)(p - (char*)d_ws);
    size_t remain = ws_size > used ? ws_size - used : 0;
    int HC = H_DIM;
    while (HC > 384 && (size_t)N_ASSIGN * HC * 2 > remain) HC >>= 1;
    unsigned short* hs = (unsigned short*)p;

    hipMemsetAsync(d_ws, 0, 1024, stream);                                      // pi, cnt, cursor, off
    hipMemsetAsync(d_out, 0, (size_t)N_TOK * C_DIM * sizeof(float), stream);    // accumulated output

    transpose_both_kernel<<<dim3(48, 16, 16), 256, 0, stream>>>(W1, W2, W1bT, W2bT);

    router_kernel<<<256, 256, 0, stream>>>(x, Wr, idx2, wgt2, pi, cntA);
    finalize_router_kernel<<<1, 64, 0, stream>>>(cntA, pi, offA, out + (size_t)N_TOK * C_DIM);
    scatter_kernel<<<N_ASSIGN / 256, 256, 0, stream>>>(idx2, wgt2, offA, cursor, tok, gwA);
    gather_kernel<<<N_ASSIGN / 4, 256, 0, stream>>>(x, tok, xg);

    // max non-empty logical blocks: sum_e ceil(M_e/128) <= 16384/128 + 7 = 135
    int nChunks = H_DIM / HC;
    for (int ci = 0; ci < nChunks; ++ci) {
        int h0 = ci * HC;
        int ny1 = HC / 128;
        int sk2 = (HC >= 1536) ? 2 : 1;   // Kseg = HC/sk2, multiple of 32
        // GEMM1: [M_e x C] @ W1^T[H x C] -> silu -> hs[. x HC]; K=1024
        moe_gemm_kernel<0><<<dim3(135 * ny1 + 8, 1, 1), 512, 0, stream>>>(
            xg, C_DIM, W1bT, C_DIM, h0, 0, C_DIM, ny1, 1,
            cntA, offA, tok, gwA, hs, HC, out);
        // GEMM2: [M_e x HC] @ W2^T[C x H] -> scaled atomic scatter; split-K
        moe_gemm_kernel<1><<<dim3(135 * 8 * sk2 + 8, 1, 1), 512, 0, stream>>>(
            hs, HC, W2bT, H_DIM, 0, h0, HC / sk2, 8, sk2,
            cntA, offA, tok, gwA, hs, HC, out);
    }
}